// Round 4
// baseline (45.576 us; speedup 1.0000x reference)
//
#include <hip/hip_runtime.h>

// Problem constants (match reference)
constexpr int V     = 50265;   // vocab size
constexpr int PADT  = 1;       // PAD token id
constexpr int BATCH = 512;
constexpr int SEQ   = 512;
constexpr int QS    = 12568;   // vocab quarter (even -> packed words align)
constexpr int HQW   = QS / 2;  // 6284 packed u32 words (2x u16) = 25.1 KB
constexpr int NPART = 64;      // one wave's worth of partials

// Kernel 1: 64 block-partials of the global non-PAD token count.
// Every slot written every call (no zero-init dependency, deterministic).
__global__ __launch_bounds__(512) void k_partial(const int4* __restrict__ ids4,
                                                 int* __restrict__ partials) {
    const int t = threadIdx.x, b = blockIdx.x;
    const int4 a = ids4[b * 1024 + t];          // 64 blk * 512 thr * 8 tok = 262144
    const int4 c4 = ids4[b * 1024 + 512 + t];
    int c = (a.x != PADT) + (a.y != PADT) + (a.z != PADT) + (a.w != PADT)
          + (c4.x != PADT) + (c4.y != PADT) + (c4.z != PADT) + (c4.w != PADT);
    #pragma unroll
    for (int off = 32; off > 0; off >>= 1) c += __shfl_down(c, off, 64);
    __shared__ int sc[8];
    if ((t & 63) == 0) sc[t >> 6] = c;
    __syncthreads();
    if (t == 0) {
        int s = 0;
        #pragma unroll
        for (int j = 0; j < 8; ++j) s += sc[j];
        partials[b] = s;
    }
}

// Kernel 2: one block per (row, half) -- each block streams TWO vocab
// quarters of its row through one 25.1 KB LDS histogram (4 blocks/CU,
// 32 waves). Row load + np-reduce + total-reduce + addend happen ONCE
// per block (was 4x per row). Output written exactly once, coalesced,
// nontemporal (streaming, evict-first in L2) -> no RFO, no re-touch.
__global__ __launch_bounds__(512) void k_fused(const int* __restrict__ ids,
                                               const int* __restrict__ partials,
                                               float* __restrict__ out) {
    __shared__ unsigned hist[HQW];
    __shared__ int s_red[8];
    __shared__ float s_add;

    const int bh = blockIdx.x;
    const int b = bh >> 1, h = bh & 1;
    const int t = threadIdx.x;

    // issue global loads immediately; latency hides under the reduces
    int pv = (t < NPART) ? partials[t] : 0;
    const int id = ids[b * SEQ + t];

    // row non-PAD length (block reduce)
    int np = (id != PADT) ? 1 : 0;
    #pragma unroll
    for (int off = 32; off > 0; off >>= 1) np += __shfl_down(np, off, 64);
    if ((t & 63) == 0) s_red[t >> 6] = np;
    __syncthreads();

    if (t < NPART) {
        // wave-parallel global total
        #pragma unroll
        for (int off = 32; off > 0; off >>= 1) pv += __shfl_down(pv, off, 64);
        if (t == 0) {
            int dl = 0;
            #pragma unroll
            for (int j = 0; j < 8; ++j) dl += s_red[j];
            // d_avg = dl / (total/BATCH); dl*BATCH <= 2^18, exact in fp32
            float d_avg = (float)dl * (float)BATCH / (float)pv;
            s_add = 1.6f * (0.25f + 0.75f * d_avg);  // k*(1-b+b*d_avg)
        }
    }
    __syncthreads();

    const float addend = s_add;
    const int sh = (t & 1) * 16;          // loop-invariant unpack shift
    float* __restrict__ orow = out + (size_t)b * V;

    #pragma unroll 1
    for (int ph = 0; ph < 2; ++ph) {
        const int q = h * 2 + ph;
        const int v0 = q * QS;
        const int vend = (v0 + QS < V) ? (v0 + QS) : V;

        // zero histogram (prior phase's readers passed the trailing barrier)
        for (int w = t; w < HQW; w += 512) hist[w] = 0u;
        __syncthreads();

        // scatter my token if it lands in this quarter (u16-packed; cnt<=512)
        if (id != PADT && id >= v0 && id < vend) {
            const int li = id - v0;
            atomicAdd(&hist[li >> 1], 1u << ((li & 1) * 16));
        }
        __syncthreads();

        // stream the quarter: lane-consecutive words (2-way broadcast reads,
        // conflict-free), 256B/wave dense stores, nontemporal.
        for (int v = v0 + t; v < vend; v += 512) {
            const int li = v - v0;
            const unsigned cw = hist[li >> 1];
            const float fc = (float)((cw >> sh) & 0xffffu);
            __builtin_nontemporal_store((fc * 2.6f) * __builtin_amdgcn_rcpf(fc + addend),
                                        &orow[v]);
        }
        __syncthreads();   // protect hist re-zero of the next phase
    }
}

extern "C" void kernel_launch(void* const* d_in, const int* in_sizes, int n_in,
                              void* d_out, int out_size, void* d_ws, size_t ws_size,
                              hipStream_t stream) {
    const int* ids = (const int*)d_in[0];   // input_ids, int32 [512*512]
    // d_in[1] = beta (unused by the reference computation)
    float* out = (float*)d_out;             // [512 * 50265] fp32
    int* partials = (int*)d_ws;             // NPART ints of scratch

    k_partial<<<NPART, 512, 0, stream>>>((const int4*)ids, partials);
    k_fused<<<BATCH * 2, 512, 0, stream>>>(ids, partials, out);
}

// Round 5
// 26.788 us; speedup vs baseline: 1.7014x; 1.7014x over previous
//
#include <hip/hip_runtime.h>

// Problem constants (match reference)
constexpr int V     = 50265;   // vocab size
constexpr int PADT  = 1;       // PAD token id
constexpr int BATCH = 512;
constexpr int SEQ   = 512;
constexpr int NSEC  = 8;       // vocab sections per row
constexpr int SS    = 6284;    // section size (even -> packed u16 words align)
constexpr int HW    = SS / 2;  // 3142 packed u32 words = 12.6 KB
constexpr int HW4   = 3144;    // rounded to uint4 multiple for fast zeroing
constexpr int NPART = 64;      // one wave's worth of partials

// Kernel 1: 64 block-partials of the global non-PAD token count.
// Every slot written every call (no zero-init dependency, deterministic).
__global__ __launch_bounds__(512) void k_partial(const int4* __restrict__ ids4,
                                                 int* __restrict__ partials) {
    const int t = threadIdx.x, b = blockIdx.x;
    const int4 a = ids4[b * 1024 + t];          // 64 blk * 512 thr * 8 tok = 262144
    const int4 c4 = ids4[b * 1024 + 512 + t];
    int c = (a.x != PADT) + (a.y != PADT) + (a.z != PADT) + (a.w != PADT)
          + (c4.x != PADT) + (c4.y != PADT) + (c4.z != PADT) + (c4.w != PADT);
    #pragma unroll
    for (int off = 32; off > 0; off >>= 1) c += __shfl_down(c, off, 64);
    __shared__ int sc[8];
    if ((t & 63) == 0) sc[t >> 6] = c;
    __syncthreads();
    if (t == 0) {
        int s = 0;
        #pragma unroll
        for (int j = 0; j < 8; ++j) s += sc[j];
        partials[b] = s;
    }
}

// Kernel 2: one 256-thread block per (row, vocab-eighth). 12.6 KB LDS hist ->
// 8 blocks/CU = 32 waves (occupancy max) with fine-grained phase interleave:
// while one block is zeroing/scattering, 7 others are streaming stores, so
// the CU's store queue stays full. Output written exactly once, coalesced,
// REGULAR stores (R4 showed nontemporal regresses streaming writes ~2x).
__global__ __launch_bounds__(256) void k_fused(const int* __restrict__ ids,
                                               const int* __restrict__ partials,
                                               float* __restrict__ out) {
    __shared__ unsigned hist[HW4];
    __shared__ int s_red[4];
    __shared__ float s_add;

    const int bs = blockIdx.x;
    const int b = bs >> 3, s = bs & 7;
    const int t = threadIdx.x;
    const int v0 = s * SS;
    const int vend = (v0 + SS < V) ? (v0 + SS) : V;

    // issue global loads immediately; latency hides under hist zeroing
    int pv = (t < NPART) ? partials[t] : 0;
    const int id0 = ids[b * SEQ + t];
    const int id1 = ids[b * SEQ + 256 + t];

    // zero histogram with 16B LDS writes (786 uint4 words / 256 thr ~ 3 iters)
    uint4* h4 = (uint4*)hist;
    const uint4 z4 = make_uint4(0u, 0u, 0u, 0u);
    #pragma unroll
    for (int w = t; w < HW4 / 4; w += 256) h4[w] = z4;
    __syncthreads();

    // scatter my 2 tokens if they land in this section (u16-packed; cnt<=512)
    if (id0 != PADT && id0 >= v0 && id0 < vend) {
        const int li = id0 - v0;
        atomicAdd(&hist[li >> 1], 1u << ((li & 1) * 16));
    }
    if (id1 != PADT && id1 >= v0 && id1 < vend) {
        const int li = id1 - v0;
        atomicAdd(&hist[li >> 1], 1u << ((li & 1) * 16));
    }

    // row non-PAD length (block reduce over 4 waves)
    int np = ((id0 != PADT) ? 1 : 0) + ((id1 != PADT) ? 1 : 0);
    #pragma unroll
    for (int off = 32; off > 0; off >>= 1) np += __shfl_down(np, off, 64);
    if ((t & 63) == 0) s_red[t >> 6] = np;
    __syncthreads();

    if (t < NPART) {
        // wave-parallel global total (loads issued at kernel entry)
        #pragma unroll
        for (int off = 32; off > 0; off >>= 1) pv += __shfl_down(pv, off, 64);
        if (t == 0) {
            int dl = s_red[0] + s_red[1] + s_red[2] + s_red[3];
            // d_avg = dl / (total/BATCH); dl*BATCH <= 2^18, exact in fp32
            float d_avg = (float)dl * (float)BATCH / (float)pv;
            s_add = 1.6f * (0.25f + 0.75f * d_avg);  // k*(1-b+b*d_avg)
        }
    }
    __syncthreads();

    const float addend = s_add;
    const int sh = (t & 1) * 16;          // loop-invariant unpack shift
    float* __restrict__ orow = out + (size_t)b * V;

    // stream this section: lane-consecutive words (2-way broadcast LDS reads,
    // conflict-free), 256B/wave dense stores.
    // fc==0 -> (0*2.6)*rcp(addend) == 0 exactly; rcp err ~1ulp << 3.4e-2.
    for (int v = v0 + t; v < vend; v += 256) {
        const unsigned cw = hist[(v - v0) >> 1];
        const float fc = (float)((cw >> sh) & 0xffffu);
        orow[v] = (fc * 2.6f) * __builtin_amdgcn_rcpf(fc + addend);
    }
}

extern "C" void kernel_launch(void* const* d_in, const int* in_sizes, int n_in,
                              void* d_out, int out_size, void* d_ws, size_t ws_size,
                              hipStream_t stream) {
    const int* ids = (const int*)d_in[0];   // input_ids, int32 [512*512]
    // d_in[1] = beta (unused by the reference computation)
    float* out = (float*)d_out;             // [512 * 50265] fp32
    int* partials = (int*)d_ws;             // NPART ints of scratch

    k_partial<<<NPART, 512, 0, stream>>>((const int4*)ids, partials);
    k_fused<<<BATCH * NSEC, 256, 0, stream>>>(ids, partials, out);
}

// Round 6
// 26.428 us; speedup vs baseline: 1.7246x; 1.0136x over previous
//
#include <hip/hip_runtime.h>

// Problem constants (match reference)
constexpr int V     = 50265;   // vocab size
constexpr int PADT  = 1;       // PAD token id
constexpr int BATCH = 512;
constexpr int SEQ   = 512;
constexpr int NSEC  = 8;       // vocab sections per row
constexpr int SS    = 6284;    // section size (even -> packed u16 words align)
constexpr int HW4   = 3144;    // 3142 packed words rounded to uint4 multiple
constexpr int NPART = 64;      // one wave's worth of partials

// Kernel 1: 64 block-partials of the global non-PAD token count.
// Every slot written every call (no zero-init dependency, deterministic).
__global__ __launch_bounds__(512) void k_partial(const int4* __restrict__ ids4,
                                                 int* __restrict__ partials) {
    const int t = threadIdx.x, b = blockIdx.x;
    const int4 a = ids4[b * 1024 + t];          // 64 blk * 512 thr * 8 tok = 262144
    const int4 c4 = ids4[b * 1024 + 512 + t];
    int c = (a.x != PADT) + (a.y != PADT) + (a.z != PADT) + (a.w != PADT)
          + (c4.x != PADT) + (c4.y != PADT) + (c4.z != PADT) + (c4.w != PADT);
    #pragma unroll
    for (int off = 32; off > 0; off >>= 1) c += __shfl_down(c, off, 64);
    __shared__ int sc[8];
    if ((t & 63) == 0) sc[t >> 6] = c;
    __syncthreads();
    if (t == 0) {
        int s = 0;
        #pragma unroll
        for (int j = 0; j < 8; ++j) s += sc[j];
        partials[b] = s;
    }
}

// Kernel 2: 2048 blocks x 256 threads = exactly 8 blocks/CU, ONE resident
// round (no second-round preamble bubble). Each block = (row, quarter):
// preamble once, then two vocab sections streamed through one 12.6 KB LDS
// histogram. Output written exactly once, coalesced, regular stores
// (R4 showed nontemporal regresses streaming writes ~2x).
__global__ __launch_bounds__(256) void k_fused(const int* __restrict__ ids,
                                               const int* __restrict__ partials,
                                               float* __restrict__ out) {
    __shared__ unsigned hist[HW4];
    __shared__ int s_red[4];
    __shared__ float s_add;

    const int bs = blockIdx.x;
    const int b = bs >> 2, h = bs & 3;   // row, quarter
    const int t = threadIdx.x;

    // issue global loads immediately; latency hides under the reduces
    int pv = (t < NPART) ? partials[t] : 0;
    const int id0 = ids[b * SEQ + t];
    const int id1 = ids[b * SEQ + 256 + t];

    // row non-PAD length (block reduce over 4 waves)
    int np = ((id0 != PADT) ? 1 : 0) + ((id1 != PADT) ? 1 : 0);
    #pragma unroll
    for (int off = 32; off > 0; off >>= 1) np += __shfl_down(np, off, 64);
    if ((t & 63) == 0) s_red[t >> 6] = np;
    __syncthreads();

    if (t < NPART) {
        // wave-parallel global total (loads issued at kernel entry)
        #pragma unroll
        for (int off = 32; off > 0; off >>= 1) pv += __shfl_down(pv, off, 64);
        if (t == 0) {
            int dl = s_red[0] + s_red[1] + s_red[2] + s_red[3];
            // d_avg = dl / (total/BATCH); dl*BATCH <= 2^18, exact in fp32
            float d_avg = (float)dl * (float)BATCH / (float)pv;
            s_add = 1.6f * (0.25f + 0.75f * d_avg);  // k*(1-b+b*d_avg)
        }
    }
    __syncthreads();

    const float addend = s_add;
    const int sh = (t & 1) * 16;          // loop-invariant unpack shift
    float* __restrict__ orow = out + (size_t)b * V;

    #pragma unroll 1
    for (int ph = 0; ph < 2; ++ph) {
        const int q = h * 2 + ph;
        const int v0 = q * SS;
        const int vend = (v0 + SS < V) ? (v0 + SS) : V;

        // zero histogram with 16B LDS writes (786 uint4 / 256 thr ~ 3 iters)
        uint4* h4 = (uint4*)hist;
        const uint4 z4 = make_uint4(0u, 0u, 0u, 0u);
        #pragma unroll
        for (int w = t; w < HW4 / 4; w += 256) h4[w] = z4;
        __syncthreads();

        // scatter my 2 tokens if in this section (u16-packed; counts <= 512)
        if (id0 != PADT && id0 >= v0 && id0 < vend) {
            const int li = id0 - v0;
            atomicAdd(&hist[li >> 1], 1u << ((li & 1) * 16));
        }
        if (id1 != PADT && id1 >= v0 && id1 < vend) {
            const int li = id1 - v0;
            atomicAdd(&hist[li >> 1], 1u << ((li & 1) * 16));
        }
        __syncthreads();

        // stream the section: lane-consecutive words (2-way broadcast LDS
        // reads, conflict-free), 256B/wave dense stores.
        // fc==0 -> (0*2.6)*rcp(addend) == 0 exactly; rcp err ~1ulp << 3.4e-2.
        for (int v = v0 + t; v < vend; v += 256) {
            const unsigned cw = hist[(v - v0) >> 1];
            const float fc = (float)((cw >> sh) & 0xffffu);
            orow[v] = (fc * 2.6f) * __builtin_amdgcn_rcpf(fc + addend);
        }
        __syncthreads();   // protect hist re-zero of the next section
    }
}

extern "C" void kernel_launch(void* const* d_in, const int* in_sizes, int n_in,
                              void* d_out, int out_size, void* d_ws, size_t ws_size,
                              hipStream_t stream) {
    const int* ids = (const int*)d_in[0];   // input_ids, int32 [512*512]
    // d_in[1] = beta (unused by the reference computation)
    float* out = (float*)d_out;             // [512 * 50265] fp32
    int* partials = (int*)d_ws;             // NPART ints of scratch

    k_partial<<<NPART, 512, 0, stream>>>((const int4*)ids, partials);
    k_fused<<<BATCH * 4, 256, 0, stream>>>(ids, partials, out);
}